// Round 8
// baseline (6082.267 us; speedup 1.0000x reference)
//
#include <hip/hip_runtime.h>

typedef __attribute__((ext_vector_type(4))) float f32x4;
typedef __attribute__((ext_vector_type(4))) int   i32x4;
typedef __attribute__((ext_vector_type(8))) short s16x8;

#define MFMA16(a, b, c)  __builtin_amdgcn_mfma_f32_16x16x32_bf16((a), (b), (c), 0, 0, 0)
#define MFMAI8(a, b, c)  __builtin_amdgcn_mfma_i32_16x16x64_i8((a), (b), (c), 0, 0, 0)

#define QINV (1.0f / 252.0f)

// ---------- bf16 helpers (RNE) ----------
__device__ inline unsigned short f2bf(float f) {
    unsigned int u = __float_as_uint(f);
    return (unsigned short)((u + 0x7FFFu + ((u >> 16) & 1u)) >> 16);
}
__device__ inline float bf2f(unsigned short b) {
    return __uint_as_float(((unsigned int)b) << 16);
}

// ---------- pack W [K][1024] f32 -> THREE bf16 levels (W_in path) ----------
__global__ __launch_bounds__(256) void k_pack3(const float* __restrict__ W,
                                               unsigned short* __restrict__ L1,
                                               unsigned short* __restrict__ L2,
                                               unsigned short* __restrict__ L3,
                                               int K) {
    int idx = blockIdx.x * 256 + threadIdx.x;
    if (idx >= K * 1024) return;
    int k = idx >> 10;
    int n = idx & 1023;
    float x = W[idx];
    unsigned short h1 = f2bf(x);  float r1 = x - bf2f(h1);
    unsigned short h2 = f2bf(r1); float r2 = r1 - bf2f(h2);
    unsigned short h3 = f2bf(r2);
    size_t o = ((size_t)(k >> 5) << 15) + ((size_t)n << 5) + (k & 31);
    L1[o] = h1; L2[o] = h2; L3[o] = h3;
}

// ---------- per-column max|W_rec| -> t1[n] = max/126 ----------
__global__ __launch_bounds__(256) void k_colmax(const float* __restrict__ W,
                                                float* __restrict__ t1) {
    __shared__ float red[256];
    int n = blockIdx.x;
    float m = 0.f;
    for (int k = threadIdx.x; k < 1024; k += 256)
        m = fmaxf(m, fabsf(W[(size_t)k * 1024 + n]));
    red[threadIdx.x] = m;
    __syncthreads();
    for (int s = 128; s > 0; s >>= 1) {
        if (threadIdx.x < s) red[threadIdx.x] = fmaxf(red[threadIdx.x], red[threadIdx.x + s]);
        __syncthreads();
    }
    if (threadIdx.x == 0) t1[n] = fmaxf(red[0], 1e-30f) * (1.0f / 126.0f);
}

// ---------- pack W_rec -> 3 i8 digits, interleaved [kt][n][lvl][64] ----------
__global__ __launch_bounds__(256) void k_packq(const float* __restrict__ W,
                                               const float* __restrict__ t1a,
                                               signed char* __restrict__ Q) {
    int idx = blockIdx.x * 256 + threadIdx.x;   // k*1024 + n
    int k = idx >> 10;
    int n = idx & 1023;
    float x = W[idx];
    float T1 = t1a[n];
    float T2 = T1 * QINV;
    float T3 = T2 * QINV;
    float q1 = rintf(x / T1);  float r1 = fmaf(-q1, T1, x);
    float q2 = rintf(r1 / T2); float r2 = fmaf(-q2, T2, r1);
    float q3 = rintf(r2 / T3);
    size_t o = ((size_t)((k >> 6) * 1024 + n)) * 192 + (k & 63);
    Q[o]       = (signed char)(int)q1;
    Q[o + 64]  = (signed char)(int)q2;
    Q[o + 128] = (signed char)(int)q3;
}

// ---------- main: 128 blocks x 16 rows, 512 thr (8 waves, 2 waves/SIMD) ----------
// Wave w covers cols {w*64..w*64+64} and {512+w*64..}, as two groups per step.
// 2-deep register double-buffer on B1/B2/A; B3 loaded per-kt (consumed after
// 8 MFMAs >= L2 latency). base2 lives in LDS. One WrQ walk per step, R4 order.
#define FSTR 770
#define LDS_SPK0   0        // i8 [16][1024] XOR-swizzled, buf0
#define LDS_SPK1   16384    // buf1
#define LDS_FUSED  32768    // f32 [16][770] = 49280 B (phases A/B only)
#define LDS_DEC    32768    // f32[1024] (after phase B; overlaps dead fused)
#define LDS_FRQ    36864
#define LDS_T1     40960
#define LDS_BASE2  45056    // f32 [16][1028] = 65792 B -> ends 110848
#define LDS_TOTAL  110848
__global__ __launch_bounds__(512, 2) void k_main(const float* __restrict__ fused,
                                                 const unsigned short* __restrict__ Wi1,
                                                 const unsigned short* __restrict__ Wi2,
                                                 const unsigned short* __restrict__ Wi3,
                                                 const float* __restrict__ b_in,
                                                 const signed char* __restrict__ WrQ,
                                                 const float* __restrict__ t1a,
                                                 const float* __restrict__ b_rec,
                                                 const float* __restrict__ rdec,
                                                 const float* __restrict__ rfrq,
                                                 const float* __restrict__ W_out,
                                                 const float* __restrict__ b_out,
                                                 float* __restrict__ out) {
    extern __shared__ __align__(16) char smem[];
    const int tid = threadIdx.x;
    const int w = tid >> 6, lane = tid & 63;
    const int llo = lane & 15, lhi = lane >> 4;
    const int r0 = blockIdx.x * 16;

    // ---- phase A: stage fused[r0:r0+16][0:768] -> LDS ----
    float* fl = (float*)(smem + LDS_FUSED);
    for (int i = tid; i < 16 * 768; i += 512) {
        int rr = i / 768, cc = i - rr * 768;
        fl[rr * FSTR + cc] = fused[(size_t)(r0 + rr) * 768 + cc];
    }
    __syncthreads();

    // ---- phase B: base = fused @ W_in + b_in (3x3-level bf16, 6 passes),
    //      both col-groups per wave ----
    f32x4 bacc[2][4] = {};
    for (int kt = 0; kt < 24; ++kt) {
        const float* ap = fl + llo * FSTR + kt * 32 + lhi * 8;
        s16x8 a1v, a2v, a3v;
#pragma unroll
        for (int j = 0; j < 8; ++j) {
            float x = ap[j];
            unsigned short h1 = f2bf(x);  float r1 = x - bf2f(h1);
            unsigned short h2 = f2bf(r1); float r2 = r1 - bf2f(h2);
            a1v[j] = (short)h1; a2v[j] = (short)h2; a3v[j] = (short)f2bf(r2);
        }
#pragma unroll
        for (int g = 0; g < 2; ++g) {
#pragma unroll
            for (int nt = 0; nt < 4; ++nt) {
                int c = g * 512 + w * 64 + nt * 16 + llo;
                size_t boff = ((size_t)(kt * 1024 + c) << 5) + lhi * 8;
                s16x8 b1 = *(const s16x8*)&Wi1[boff];
                s16x8 b2 = *(const s16x8*)&Wi2[boff];
                s16x8 b3 = *(const s16x8*)&Wi3[boff];
                bacc[g][nt] = MFMA16(a1v, b1, bacc[g][nt]);
                bacc[g][nt] = MFMA16(a1v, b2, bacc[g][nt]);
                bacc[g][nt] = MFMA16(a2v, b1, bacc[g][nt]);
                bacc[g][nt] = MFMA16(a2v, b2, bacc[g][nt]);
                bacc[g][nt] = MFMA16(a1v, b3, bacc[g][nt]);
                bacc[g][nt] = MFMA16(a3v, b1, bacc[g][nt]);
            }
        }
    }
    __syncthreads();   // all waves done reading fused; region becomes params/base2

    // ---- params (2 cols/thread) ----
    float* ldsDec = (float*)(smem + LDS_DEC);
    float* ldsFrq = (float*)(smem + LDS_FRQ);
    float* ldsT1  = (float*)(smem + LDS_T1);
    for (int c = tid; c < 1024; c += 512) {
        ldsDec[c] = (float)(0.55 + 0.4 / (1.0 + exp(-(double)rdec[c])));
        ldsFrq[c] = (float)(0.10 + 0.9 / (1.0 + exp(-(double)rfrq[c])));
        ldsT1[c]  = t1a[c];
    }

    // ---- base2 -> LDS; inline t=0; spikes(0) -> SPK0 ----
    float mem[2][4][4], res[2][4][4];
    unsigned int pooled_pk[2][4] = {};
    float* b2 = (float*)(smem + LDS_BASE2);
#pragma unroll
    for (int g = 0; g < 2; ++g) {
#pragma unroll
        for (int nt = 0; nt < 4; ++nt) {
            int c = g * 512 + w * 64 + nt * 16 + llo;
            float bb = b_in[c];
            float brv = b_rec[c];
#pragma unroll
            for (int fr = 0; fr < 4; ++fr) {
                int row = lhi * 4 + fr;
                float b0 = __fadd_rn(bacc[g][nt][fr], bb);
                b2[row * 1028 + c] = __fadd_rn(b0, brv);
                float m_ = __fadd_rn(0.f, b0);
                int s = (m_ > 1.0f) ? 1 : 0;
                res[g][nt][fr] = 0.f;
                mem[g][nt][fr] = __fadd_rn(m_, -(float)s);
                pooled_pk[g][nt] += (unsigned int)s << (8 * fr);
                *(unsigned char*)(smem + LDS_SPK0 + ((row * 1024 + c) ^ ((row & 7) << 4))) =
                    (unsigned char)s;
            }
        }
    }
    __syncthreads();

    // ---- phase C: steps 1..31 ----
    const int ax = (llo & 7) << 4;
    for (int t = 1; t < 32; ++t) {
        const char* ab = smem + ((t - 1) & 1) * 16384 + llo * 1024;
        char* wb = smem + (t & 1) * 16384;
#pragma unroll
        for (int g = 0; g < 2; ++g) {
            const signed char* bp0 = WrQ + ((size_t)(g * 512 + w * 64 + llo)) * 192
                                         + (size_t)(lhi * 16);
            i32x4 q1a[4] = {}, q2a[4] = {}, q3a[4] = {};
            i32x4 B1d[2][4], B2d[2][4], B3c[4], Ad[2];
#pragma unroll
            for (int nt = 0; nt < 4; ++nt) {
                B1d[0][nt] = *(const i32x4*)(bp0 + nt * 3072);
                B2d[0][nt] = *(const i32x4*)(bp0 + nt * 3072 + 64);
            }
            Ad[0] = *(const i32x4*)(ab + ((lhi * 16) ^ ax));
#pragma unroll
            for (int kt = 0; kt < 16; ++kt) {
                const int cur = kt & 1, nxt = cur ^ 1;
                const signed char* bc = bp0 + (size_t)kt * 196608;
#pragma unroll
                for (int nt = 0; nt < 4; ++nt)
                    B3c[nt] = *(const i32x4*)(bc + nt * 3072 + 128);
                if (kt < 15) {
                    const signed char* bq = bp0 + (size_t)(kt + 1) * 196608;
#pragma unroll
                    for (int nt = 0; nt < 4; ++nt) {
                        B1d[nxt][nt] = *(const i32x4*)(bq + nt * 3072);
                        B2d[nxt][nt] = *(const i32x4*)(bq + nt * 3072 + 64);
                    }
                    Ad[nxt] = *(const i32x4*)(ab + ((((kt + 1) * 64) + lhi * 16) ^ ax));
                }
                // q1/q2 first (operands long-resident), q3 last (B3c covered by 8 MFMAs)
#pragma unroll
                for (int nt = 0; nt < 4; ++nt) q1a[nt] = MFMAI8(Ad[cur], B1d[cur][nt], q1a[nt]);
#pragma unroll
                for (int nt = 0; nt < 4; ++nt) q2a[nt] = MFMAI8(Ad[cur], B2d[cur][nt], q2a[nt]);
#pragma unroll
                for (int nt = 0; nt < 4; ++nt) q3a[nt] = MFMAI8(Ad[cur], B3c[nt], q3a[nt]);
            }
            // state update, group g
#pragma unroll
            for (int nt = 0; nt < 4; ++nt) {
                int c = g * 512 + w * 64 + nt * 16 + llo;
                float dcc = ldsDec[c], fqc = ldsFrq[c], t1c = ldsT1[c];
#pragma unroll
                for (int fr = 0; fr < 4; ++fr) {
                    int row = lhi * 4 + fr;
                    float s3 = (float)q3a[nt][fr];
                    float s2 = fmaf(s3, QINV, (float)q2a[nt][fr]);
                    float rec = __fmul_rn(fmaf(s2, QINV, (float)q1a[nt][fr]), t1c);
                    float drive = __fadd_rn(b2[row * 1028 + c], rec);
                    float rnew = __fadd_rn(__fmul_rn(dcc, res[g][nt][fr]),
                                           __fmul_rn(fqc, mem[g][nt][fr]));
                    float tt = __fadd_rn(__fmul_rn(dcc, mem[g][nt][fr]), drive);
                    float m_ = __fadd_rn(tt, -rnew);
                    int s = (m_ > 1.0f) ? 1 : 0;
                    res[g][nt][fr] = rnew;
                    mem[g][nt][fr] = __fadd_rn(m_, -(float)s);
                    pooled_pk[g][nt] += (unsigned int)s << (8 * fr);
                    *(unsigned char*)(wb + ((row * 1024 + c) ^ ((row & 7) << 4))) =
                        (unsigned char)s;
                }
            }
        }
        __syncthreads();
    }

    // ---- phase D: pooled/32 -> LDS (base2 region, dead), f64 dot W_out ----
    float* plds = (float*)(smem + LDS_BASE2);
#pragma unroll
    for (int g = 0; g < 2; ++g)
#pragma unroll
        for (int nt = 0; nt < 4; ++nt) {
            int c = g * 512 + w * 64 + nt * 16 + llo;
#pragma unroll
            for (int fr = 0; fr < 4; ++fr)
                plds[(lhi * 4 + fr) * 1028 + c] =
                    (float)((pooled_pk[g][nt] >> (8 * fr)) & 255u) * 0.03125f;
        }
    __syncthreads();
    if (tid < 256) {
        int row = tid >> 4, o = tid & 15;
        double s = 0.0;
        for (int h = 0; h < 1024; ++h)
            s += (double)plds[row * 1028 + h] * (double)W_out[h * 16 + o];
        out[(size_t)(r0 + row) * 16 + o] = __fadd_rn((float)s, b_out[o]);
    }
}

extern "C" void kernel_launch(void* const* d_in, const int* in_sizes, int n_in,
                              void* d_out, int out_size, void* d_ws, size_t ws_size,
                              hipStream_t stream) {
    const float* fused = (const float*)d_in[0];
    const float* W_in  = (const float*)d_in[1];
    const float* b_in  = (const float*)d_in[2];
    const float* W_rec = (const float*)d_in[3];
    const float* b_rec = (const float*)d_in[4];
    const float* W_out = (const float*)d_in[5];
    const float* b_out = (const float*)d_in[6];
    const float* rdec  = (const float*)d_in[7];
    const float* rfrq  = (const float*)d_in[8];

    // ws: WrQ 3MB | t1 4KB | Wi1/2/3 4.5MB  (total ~7.75MB)
    char* ws = (char*)d_ws;
    signed char*    WrQ = (signed char*)(ws);
    float*          t1a = (float*)(ws + (3u << 20));
    unsigned short* Wi1 = (unsigned short*)(ws + (3u << 20) + (1u << 18));
    unsigned short* Wi2 = (unsigned short*)(ws + (3u << 20) + (1u << 18) + (3u << 19));
    unsigned short* Wi3 = (unsigned short*)(ws + (3u << 20) + (1u << 18) + (6u << 19));
    float* out = (float*)d_out;

    hipFuncSetAttribute((const void*)k_main,
                        hipFuncAttributeMaxDynamicSharedMemorySize, LDS_TOTAL);

    hipLaunchKernelGGL(k_colmax, dim3(1024), dim3(256), 0, stream, W_rec, t1a);
    hipLaunchKernelGGL(k_packq, dim3(4096), dim3(256), 0, stream, W_rec, t1a, WrQ);
    hipLaunchKernelGGL(k_pack3, dim3(3072), dim3(256), 0, stream, W_in, Wi1, Wi2, Wi3, 768);
    hipLaunchKernelGGL(k_main, dim3(128), dim3(512), LDS_TOTAL, stream,
                       fused, Wi1, Wi2, Wi3, b_in, WrQ, t1a, b_rec,
                       rdec, rfrq, W_out, b_out, out);
}